// Round 1
// baseline (160.787 us; speedup 1.0000x reference)
//
#include <hip/hip_runtime.h>
#include <math.h>

// Problem constants (fixed by setup_inputs): B=32, C=1, H=W=512.
constexpr int HW_SIZE = 512 * 512;      // 262144 = 1 << 18
constexpr int NB      = 32;
constexpr int N       = NB * HW_SIZE;   // 8,388,608 floats per big array
constexpr int N4      = N / 4;          // float4 count

// Grid-stride masked-BCE partial reduction.
// acc[0] = sum(bce * m), acc[1] = sum(m)
__global__ __launch_bounds__(256) void loss_reduce(
    const float4* __restrict__ x4,
    const float*  __restrict__ label,
    const float4* __restrict__ pm4,
    const float4* __restrict__ nm4,
    float* __restrict__ acc) {
  float s_bce = 0.0f;
  float s_cnt = 0.0f;

  const int stride = gridDim.x * blockDim.x;
  for (int i = blockIdx.x * blockDim.x + threadIdx.x; i < N4; i += stride) {
    const float4 xv = x4[i];
    const float4 pv = pm4[i];
    const float4 nv = nm4[i];
    // batch index of element 4*i: (4*i) >> 18 == i >> 16. All 4 lanes of a
    // float4 share the same batch (HW is a multiple of 4).
    const float y = label[i >> 16];

    const float xs[4] = {xv.x, xv.y, xv.z, xv.w};
    const float ps[4] = {pv.x, pv.y, pv.z, pv.w};
    const float ns[4] = {nv.x, nv.y, nv.z, nv.w};
#pragma unroll
    for (int j = 0; j < 4; ++j) {
      const float m  = (ps[j] > 0.5f && ns[j] > 0.5f) ? 1.0f : 0.0f;
      const float xi = xs[j];
      // bce = max(x,0) - x*y + log1p(exp(-|x|))
      const float bce = fmaxf(xi, 0.0f) - xi * y + log1pf(expf(-fabsf(xi)));
      s_bce += bce * m;
      s_cnt += m;
    }
  }

  // Wave64 butterfly reduce.
#pragma unroll
  for (int off = 32; off > 0; off >>= 1) {
    s_bce += __shfl_down(s_bce, off);
    s_cnt += __shfl_down(s_cnt, off);
  }

  // Cross-wave reduce (256 threads = 4 waves).
  __shared__ float sb[4];
  __shared__ float sc[4];
  const int lane = threadIdx.x & 63;
  const int wave = threadIdx.x >> 6;
  if (lane == 0) {
    sb[wave] = s_bce;
    sc[wave] = s_cnt;
  }
  __syncthreads();
  if (threadIdx.x == 0) {
    const float tb = sb[0] + sb[1] + sb[2] + sb[3];
    const float tc = sc[0] + sc[1] + sc[2] + sc[3];
    atomicAdd(&acc[0], tb);
    atomicAdd(&acc[1], tc);
  }
}

__global__ void loss_finalize(const float* __restrict__ acc,
                              float* __restrict__ out) {
  out[0] = acc[0] / fmaxf(acc[1], 1.0f);
}

extern "C" void kernel_launch(void* const* d_in, const int* in_sizes, int n_in,
                              void* d_out, int out_size, void* d_ws, size_t ws_size,
                              hipStream_t stream) {
  const float4* x4    = (const float4*)d_in[0];  // cancer_logits
  const float*  label = (const float*)d_in[1];   // label (32,)
  const float4* pm4   = (const float4*)d_in[2];  // prostate_mask
  const float4* nm4   = (const float4*)d_in[3];  // needle_mask
  float* acc = (float*)d_ws;   // [0]=sum bce*m, [1]=sum m
  float* out = (float*)d_out;

  // d_ws is poisoned 0xAA before every launch — zero the accumulators.
  hipMemsetAsync(acc, 0, 2 * sizeof(float), stream);

  // 2048 blocks x 256 threads = 524288 threads; 4 float4 iters per thread.
  loss_reduce<<<2048, 256, 0, stream>>>(x4, label, pm4, nm4, acc);
  loss_finalize<<<1, 1, 0, stream>>>(acc, out);
}